// Round 5
// baseline (815.110 us; speedup 1.0000x reference)
//
#include <hip/hip_runtime.h>

// ---------------------------------------------------------------------------
// RNN_83313775608289: 4-layer tanh RNN (H=64) + FC, B=512, T=1024, D_in=52.
// SINGLE fused kernel (r5): the old pre0 pass is folded into the pipeline.
//   One block (8 waves, 512 thr) per batch row; 512 blocks = 2 blocks/CU.
//   4 time steps per barrier interval (263 intervals), skew 1 interval/wave:
//     wave 0: h0[4k..4k+3] = tanh(pre0 + Whh0 h0[.-1])     k' = k-0
//     wave 1: P1[..] = Wih1 h0[..]   PLUS pre0 production  k' = k-1
//     wave 2: h1[..] = tanh(P1 + Whh1 h1[.-1] + b1)        k' = k-2
//     wave 3: P2[..] = Wih2 h1[..]                         k' = k-3
//     wave 4: h2[..] = tanh(P2 + Whh2 h2[.-1] + b2)        k' = k-4
//     wave 5: P3[..] = Wih3 h2[..]                         k' = k-5
//     wave 6: h3[..] = tanh(P3 + Whh3 h3[.-1] + b3)        k' = k-6
//     wave 7: out[..] = Wfc h3[..] + bfc                   k' = k-7
//   Wave-1 extra duty (it has ~4000 cy of slack per ~4680 cy interval):
//     at step k: produce pre[k+1] from LDS x-stage slot (k+1)&1 into
//     PB[0][k&1]; ds_write x-tile for interval k+2 (from regs) into x-stage
//     slot k&1; issue global x load for interval k+3 (832 B contiguous,
//     lanes 0..51, latency hidden under 2 intervals). All ordering comes
//     from the existing per-step barrier; slot parities are disjoint per
//     phase. Eliminates the pre0 kernel, its launch, and the 64 MiB
//     pre0p HBM write+readback; pre is now f32 (no f16 rounding).
//   h handoff: LDS f16 rows, uniform ds_read_b128 broadcast -> v_dot2.
//   PB (pre/P) handoff: LDS f32 per-lane. Weights stay in VGPRs.
// ---------------------------------------------------------------------------

typedef __fp16 h2 __attribute__((ext_vector_type(2)));

__device__ __forceinline__ h2 pk2(float a, float b) {
#if __has_builtin(__builtin_amdgcn_cvt_pkrtz)
  return __builtin_amdgcn_cvt_pkrtz(a, b);
#else
  h2 r; r.x = (__fp16)a; r.y = (__fp16)b; return r;
#endif
}

__device__ __forceinline__ float fdot2f(h2 a, h2 b, float c) {
#if __has_builtin(__builtin_amdgcn_fdot2)
  return __builtin_amdgcn_fdot2(a, b, c, false);
#else
  return c + (float)a.x * (float)b.x + (float)a.y * (float)b.y;
#endif
}

__device__ __forceinline__ h2 bc(unsigned int u) {
  return __builtin_bit_cast(h2, u);
}

__device__ __forceinline__ unsigned int ubc(h2 v) {
  return __builtin_bit_cast(unsigned int, v);
}

__device__ __forceinline__ float fast_tanh(float x) {
  float e = __expf(2.0f * x);          // overflow -> +inf -> result 1.0 (ok)
#if __has_builtin(__builtin_amdgcn_rcpf)
  return 1.0f - 2.0f * __builtin_amdgcn_rcpf(e + 1.0f);
#else
  return 1.0f - 2.0f / (e + 1.0f);
#endif
}

#define T_STEPS 1024

// 64-wide GEMV: 8 uniform ds_read_b128 + 32 dot2 in 4 chains. Macro (not fn)
// so w[] (read from enclosing scope) stays compile-time-indexed -> registers.
#define GEMV64(RES, HPTR, INIT)                               \
  do {                                                        \
    const uint4* hp_ = (const uint4*)(HPTR);                  \
    float a0_ = (INIT), a1_ = 0.f, a2_ = 0.f, a3_ = 0.f;      \
    _Pragma("unroll")                                         \
    for (int q_ = 0; q_ < 8; ++q_) {                          \
      uint4 u_ = hp_[q_];                                     \
      a0_ = fdot2f(bc(u_.x), w[4 * q_ + 0], a0_);             \
      a1_ = fdot2f(bc(u_.y), w[4 * q_ + 1], a1_);             \
      a2_ = fdot2f(bc(u_.z), w[4 * q_ + 2], a2_);             \
      a3_ = fdot2f(bc(u_.w), w[4 * q_ + 3], a3_);             \
    }                                                         \
    RES = (a0_ + a1_) + (a2_ + a3_);                          \
  } while (0)

// 52(+4 zero-pad)-wide pre GEMV: 7 uniform ds_read_b128 + 28 dot2, 4 chains.
// Uses w0[]/bias0 from enclosing scope; pads (w0[26..27], x pairs 26..27)
// are BOTH zeroed so padded products are exactly 0 (no 0*garbage NaN).
#define PREGEMV(RES, XPTR)                                    \
  do {                                                        \
    const uint4* xp_ = (const uint4*)(XPTR);                  \
    float a0_ = bias0, a1_ = 0.f, a2_ = 0.f, a3_ = 0.f;       \
    _Pragma("unroll")                                         \
    for (int q_ = 0; q_ < 7; ++q_) {                          \
      uint4 u_ = xp_[q_];                                     \
      a0_ = fdot2f(bc(u_.x), w0[4 * q_ + 0], a0_);            \
      a1_ = fdot2f(bc(u_.y), w0[4 * q_ + 1], a1_);            \
      a2_ = fdot2f(bc(u_.z), w0[4 * q_ + 2], a2_);            \
      a3_ = fdot2f(bc(u_.w), w0[4 * q_ + 3], a3_);            \
    }                                                         \
    RES = (a0_ + a1_) + (a2_ + a3_);                          \
  } while (0)

__global__ __launch_bounds__(512, 4) void rnn_fused(
    const float* __restrict__ x, const float* __restrict__ Wih0,
    const float* __restrict__ bih0, const float* __restrict__ bhh0,
    const float* __restrict__ Whh0, const float* __restrict__ Wih,
    const float* __restrict__ Whh, const float* __restrict__ bih,
    const float* __restrict__ bhh, const float* __restrict__ Wfc,
    const float* __restrict__ bfc, float* __restrict__ out) {
  const int tid  = threadIdx.x;
  const int lane = tid & 63;
  const int wv   = __builtin_amdgcn_readfirstlane(tid >> 6);  // scalar 0..7
  const int b    = blockIdx.x;

  // [layer][interval-slot][step-within-interval][lane]
  __shared__ __attribute__((aligned(16))) __fp16 hbuf[4][2][4][64];  // 4 KiB
  // PB[0] = pre (input part of layer 0); PB[L] = P_L for L=1..3.     8 KiB
  __shared__ __attribute__((aligned(16))) float PB[4][2][4][64];
  // x-stage: [slot][t-within-interval][28 f16-pairs] (26 data + 2 zero pad)
  __shared__ __attribute__((aligned(16))) unsigned int pxs[2][4][28];  // 896 B

  // zero-init hbuf (h[t=-1] = 0): 4096 B = 1024 floats, blockDim = 512
  ((float*)hbuf)[tid]       = 0.f;
  ((float*)hbuf)[tid + 512] = 0.f;

  // role/weights per wave (wv scalar -> role/L/W scalar)
  const float* W;
  float bias = 0.f;
  int role, L;
  if (wv == 7) {
    role = 2; L = 3; W = Wfc; bias = bfc[lane];
  } else if ((wv & 1) == 0) {
    role = 0; L = wv >> 1;
    W = (L == 0) ? Whh0 : (Whh + (L - 1) * 4096);
    if (L > 0) bias = bih[(L - 1) * 64 + lane] + bhh[(L - 1) * 64 + lane];
  } else {
    role = 1; L = (wv + 1) >> 1;
    W = Wih + (L - 1) * 4096;
  }

  h2 w[32];
  {
    const float2* wsrc = (const float2*)(W + lane * 64);
#pragma unroll
    for (int k = 0; k < 32; ++k) {
      float2 v = wsrc[k];
      w[k] = pk2(v.x, v.y);
    }
  }

  // ---- wave-1 extra state: Wih0 row (per-lane), bias0, x prefetch pipeline
  h2 w0[28];
  float bias0 = 0.f;
  float4 xr = {0.f, 0.f, 0.f, 0.f};                 // x regs for interval k+3
  const float4* xg = (const float4*)(x + (long)b * T_STEPS * 52);
  const int xrow = (lane / 13) & 3;                 // t-within-interval
  const int xcol = lane % 13;                       // float4 index in row
  const bool xact = (lane < 52);                    // 52 float4 per interval

  if (wv == 1) {
    const float2* w2 = (const float2*)(Wih0 + lane * 52);
#pragma unroll
    for (int k = 0; k < 26; ++k) {
      float2 v = w2[k];
      w0[k] = pk2(v.x, v.y);
    }
    w0[26] = pk2(0.f, 0.f);
    w0[27] = pk2(0.f, 0.f);
    bias0 = bih0[lane] + bhh0[lane];
    // zero the 2 pad pairs of every staged row (2 slots * 4 rows * 2 pads)
    if (lane < 16) pxs[lane >> 3][(lane >> 1) & 3][26 + (lane & 1)] = 0u;
    // prologue: intervals 0,1 staged to LDS; interval 2 held in regs
    float4 xa = {0.f, 0.f, 0.f, 0.f}, xb = {0.f, 0.f, 0.f, 0.f};
    if (xact) {
      xa = xg[0 * 52 + lane];
      xb = xg[1 * 52 + lane];
      xr = xg[2 * 52 + lane];
      pxs[0][xrow][2 * xcol]     = ubc(pk2(xa.x, xa.y));
      pxs[0][xrow][2 * xcol + 1] = ubc(pk2(xa.z, xa.w));
      pxs[1][xrow][2 * xcol]     = ubc(pk2(xb.x, xb.y));
      pxs[1][xrow][2 * xcol + 1] = ubc(pk2(xb.z, xb.w));
    }
  }
  __syncthreads();

  if (wv == 1) {
    // pre[interval 0] -> PB[0][slot 1] (wave 0 reads rd=(0-1)&1=1 at k=0)
    float pv;
    PREGEMV(pv, pxs[0][0]); PB[0][1][0][lane] = pv;
    PREGEMV(pv, pxs[0][1]); PB[0][1][1][lane] = pv;
    PREGEMV(pv, pxs[0][2]); PB[0][1][2][lane] = pv;
    PREGEMV(pv, pxs[0][3]); PB[0][1][3][lane] = pv;
  }
  __syncthreads();

  float* op = out + (long)b * T_STEPS * 64 + lane;

#pragma unroll 1
  for (int k = 0; k < 256 + 7; ++k) {
    const unsigned kk = (unsigned)(k - wv);  // interval index for this wave
    const int rd = (k - 1) & 1;
    const int wr = k & 1;
    if (kk < 256u) {
      if (role == 0) {
        // 4 serial steps: t0 = 4*kk .. t0+3; input parts from PB[L][rd]
        float p0_ = PB[L][rd][0][lane];
        float p1_ = PB[L][rd][1][lane];
        float p2_ = PB[L][rd][2][lane];
        float p3_ = PB[L][rd][3][lane];
        float hv;
        GEMV64(hv, hbuf[L][rd][3], bias);     // h[t0-1] from prev interval
        float h0v = fast_tanh(hv + p0_);
        hbuf[L][wr][0][lane] = (__fp16)h0v;
        GEMV64(hv, hbuf[L][wr][0], bias);     // intra-wave readback
        float h1v = fast_tanh(hv + p1_);
        hbuf[L][wr][1][lane] = (__fp16)h1v;
        GEMV64(hv, hbuf[L][wr][1], bias);
        float h2v = fast_tanh(hv + p2_);
        hbuf[L][wr][2][lane] = (__fp16)h2v;
        GEMV64(hv, hbuf[L][wr][2], bias);
        float h3v = fast_tanh(hv + p3_);
        hbuf[L][wr][3][lane] = (__fp16)h3v;
      } else if (role == 1) {
        // 4 independent GEMVs: P_L[t] = Wih_L h_{L-1}[t]
        float q0, q1, q2, q3;
        GEMV64(q0, hbuf[L - 1][rd][0], 0.f);
        GEMV64(q1, hbuf[L - 1][rd][1], 0.f);
        GEMV64(q2, hbuf[L - 1][rd][2], 0.f);
        GEMV64(q3, hbuf[L - 1][rd][3], 0.f);
        PB[L][wr][0][lane] = q0;
        PB[L][wr][1][lane] = q1;
        PB[L][wr][2][lane] = q2;
        PB[L][wr][3][lane] = q3;
      } else {
        // 4 independent GEMVs: out[t] = Wfc h3[t] + bfc
        float q0, q1, q2, q3;
        GEMV64(q0, hbuf[3][rd][0], bias);
        GEMV64(q1, hbuf[3][rd][1], bias);
        GEMV64(q2, hbuf[3][rd][2], bias);
        GEMV64(q3, hbuf[3][rd][3], bias);
        op[0]   = q0;
        op[64]  = q1;
        op[128] = q2;
        op[192] = q3;
        op += 256;
      }
    }
    // ---- wave-1 pre0 pipeline (independent of kk window; guarded by k) ----
    if (wv == 1) {
      if (k <= 254) {
        // produce pre[jc=k+1] from x-stage slot (k+1)&1 into PB[0][k&1]
        // (consumer wave 0 at step k+1 reads rd = k&1)
        const unsigned int* xsrc = &pxs[(k + 1) & 1][0][0];
        float pv;
        PREGEMV(pv, xsrc + 0 * 28); PB[0][wr][0][lane] = pv;
        PREGEMV(pv, xsrc + 1 * 28); PB[0][wr][1][lane] = pv;
        PREGEMV(pv, xsrc + 2 * 28); PB[0][wr][2][lane] = pv;
        PREGEMV(pv, xsrc + 3 * 28); PB[0][wr][3][lane] = pv;
      }
      if (k <= 253 && xact) {
        // stage x for interval jn=k+2 into slot k&1 (read last step ✓),
        // then prefetch interval k+3 into regs (2 intervals of latency)
        float4 xw = xr;
        if (k <= 252) xr = xg[(k + 3) * 52 + lane];
        pxs[k & 1][xrow][2 * xcol]     = ubc(pk2(xw.x, xw.y));
        pxs[k & 1][xrow][2 * xcol + 1] = ubc(pk2(xw.z, xw.w));
      }
    }
    __syncthreads();  // uniform: every thread, every interval
  }
}

// ---------------------------------------------------------------------------
extern "C" void kernel_launch(void* const* d_in, const int* in_sizes, int n_in,
                              void* d_out, int out_size, void* d_ws,
                              size_t ws_size, hipStream_t stream) {
  const float* x    = (const float*)d_in[0];
  const float* Wih0 = (const float*)d_in[1];
  const float* Whh0 = (const float*)d_in[2];
  const float* bih0 = (const float*)d_in[3];
  const float* bhh0 = (const float*)d_in[4];
  const float* Wih  = (const float*)d_in[5];
  const float* Whh  = (const float*)d_in[6];
  const float* bih  = (const float*)d_in[7];
  const float* bhh  = (const float*)d_in[8];
  const float* Wfc  = (const float*)d_in[9];
  const float* bfc  = (const float*)d_in[10];
  float* out = (float*)d_out;

  const int B = in_sizes[0] / (T_STEPS * 52);  // 512
  (void)d_ws; (void)ws_size;                   // workspace no longer needed

  rnn_fused<<<B, 512, 0, stream>>>(x, Wih0, bih0, bhh0, Whh0, Wih, Whh, bih,
                                   bhh, Wfc, bfc, out);
}

// Round 7
// 708.796 us; speedup vs baseline: 1.1500x; 1.1500x over previous
//
#include <hip/hip_runtime.h>

// ---------------------------------------------------------------------------
// RNN_83313775608289: 4-layer tanh RNN (H=64) + FC, B=512, T=1024, D_in=52.
// SINGLE fused kernel (r6): pre0 folded into the pipeline, with its work
// SPLIT across the three slack role-1 waves so no wave's live register set
// exceeds the 64-VGPR occupancy boundary (r5 piled w[32]+w0[28]+xr[4] onto
// wave 1 -> spill/remat inside the loop -> every wave stalled behind it at
// the barrier: 713us, VALUBusy 52%, +14MB scratch writes).
//   One block (8 waves, 512 thr) per batch row; 512 blocks = 2 blocks/CU.
//   4 time steps per barrier interval (263 intervals), skew 1 interval/wave:
//     wave 0: h0[4k..4k+3] = tanh(preA+preB + Whh0 h0[.-1])  k' = k-0
//     wave 1: P1[..] = Wih1 h0[..]  + pre partial d=0..31    k' = k-1
//     wave 2: h1[..] = tanh(P1 + Whh1 h1[.-1] + b1)          k' = k-2
//     wave 3: P2[..] = Wih2 h1[..]  + pre partial d=32..51   k' = k-3
//     wave 4: h2[..] = tanh(P2 + Whh2 h2[.-1] + b2)          k' = k-4
//     wave 5: P3[..] = Wih3 h2[..]  + x-tile stage/prefetch  k' = k-5
//     wave 6: h3[..] = tanh(P3 + Whh3 h3[.-1] + b3)          k' = k-6
//     wave 7: out[..] = Wfc h3[..] + bfc                     k' = k-7
//   Pipeline (all ordering via the per-step barrier; slot parities disjoint):
//     step k: waves 1/3 produce pre partials for interval k+1 from x-stage
//             slot (k+1)&1 into PB[0]/PBb slot k&1 (consumed at k+1, rd=k&1);
//             wave 5 ds_writes x-tile for interval k+2 into slot k&1 (from
//             regs; read at k+1 as slot (k+2)&1), then issues the global x
//             load for interval k+3 (832 B contiguous, lanes 0..51).
//   Eliminates the pre0 kernel, its launch, and the 64 MiB pre0p HBM
//   write+readback; pre is f32 end-to-end (no f16 rounding of pre).
//   h handoff: LDS f16 rows, uniform ds_read_b128 broadcast -> v_dot2.
// ---------------------------------------------------------------------------

typedef __fp16 h2 __attribute__((ext_vector_type(2)));

__device__ __forceinline__ h2 pk2(float a, float b) {
#if __has_builtin(__builtin_amdgcn_cvt_pkrtz)
  return __builtin_amdgcn_cvt_pkrtz(a, b);
#else
  h2 r; r.x = (__fp16)a; r.y = (__fp16)b; return r;
#endif
}

__device__ __forceinline__ float fdot2f(h2 a, h2 b, float c) {
#if __has_builtin(__builtin_amdgcn_fdot2)
  return __builtin_amdgcn_fdot2(a, b, c, false);
#else
  return c + (float)a.x * (float)b.x + (float)a.y * (float)b.y;
#endif
}

__device__ __forceinline__ h2 bc(unsigned int u) {
  return __builtin_bit_cast(h2, u);
}

__device__ __forceinline__ unsigned int ubc(h2 v) {
  return __builtin_bit_cast(unsigned int, v);
}

__device__ __forceinline__ float fast_tanh(float x) {
  float e = __expf(2.0f * x);          // overflow -> +inf -> result 1.0 (ok)
#if __has_builtin(__builtin_amdgcn_rcpf)
  return 1.0f - 2.0f * __builtin_amdgcn_rcpf(e + 1.0f);
#else
  return 1.0f - 2.0f / (e + 1.0f);
#endif
}

#define T_STEPS 1024

// 64-wide GEMV: 8 uniform ds_read_b128 + 32 dot2 in 4 chains. Macro (not fn)
// so w[] (read from enclosing scope) stays compile-time-indexed -> registers.
#define GEMV64(RES, HPTR, INIT)                               \
  do {                                                        \
    const uint4* hp_ = (const uint4*)(HPTR);                  \
    float a0_ = (INIT), a1_ = 0.f, a2_ = 0.f, a3_ = 0.f;      \
    _Pragma("unroll")                                         \
    for (int q_ = 0; q_ < 8; ++q_) {                          \
      uint4 u_ = hp_[q_];                                     \
      a0_ = fdot2f(bc(u_.x), w[4 * q_ + 0], a0_);             \
      a1_ = fdot2f(bc(u_.y), w[4 * q_ + 1], a1_);             \
      a2_ = fdot2f(bc(u_.z), w[4 * q_ + 2], a2_);             \
      a3_ = fdot2f(bc(u_.w), w[4 * q_ + 3], a3_);             \
    }                                                         \
    RES = (a0_ + a1_) + (a2_ + a3_);                          \
  } while (0)

// half-width pre GEMV: 4 uniform ds_read_b128 + 16 dot2 in 4 chains, over
// 16 f16-pairs. Reads w0[] from enclosing scope. Pads are zero on BOTH the
// weight and x sides (no 0*garbage).
#define PREGEMV16(RES, XPTR, INIT)                            \
  do {                                                        \
    const uint4* xp_ = (const uint4*)(XPTR);                  \
    float a0_ = (INIT), a1_ = 0.f, a2_ = 0.f, a3_ = 0.f;      \
    _Pragma("unroll")                                         \
    for (int q_ = 0; q_ < 4; ++q_) {                          \
      uint4 u_ = xp_[q_];                                     \
      a0_ = fdot2f(bc(u_.x), w0[4 * q_ + 0], a0_);            \
      a1_ = fdot2f(bc(u_.y), w0[4 * q_ + 1], a1_);            \
      a2_ = fdot2f(bc(u_.z), w0[4 * q_ + 2], a2_);            \
      a3_ = fdot2f(bc(u_.w), w0[4 * q_ + 3], a3_);            \
    }                                                         \
    RES = (a0_ + a1_) + (a2_ + a3_);                          \
  } while (0)

__global__ __launch_bounds__(512, 4) void rnn_fused(
    const float* __restrict__ x, const float* __restrict__ Wih0,
    const float* __restrict__ bih0, const float* __restrict__ bhh0,
    const float* __restrict__ Whh0, const float* __restrict__ Wih,
    const float* __restrict__ Whh, const float* __restrict__ bih,
    const float* __restrict__ bhh, const float* __restrict__ Wfc,
    const float* __restrict__ bfc, float* __restrict__ out) {
  const int tid  = threadIdx.x;
  const int lane = tid & 63;
  const int wv   = __builtin_amdgcn_readfirstlane(tid >> 6);  // scalar 0..7
  const int b    = blockIdx.x;

  // [layer][interval-slot][step-within-interval][lane]
  __shared__ __attribute__((aligned(16))) __fp16 hbuf[4][2][4][64];  // 4 KiB
  // PB[0] = pre partial A (d 0..31, +bias); PB[L] = P_L for L=1..3.  8 KiB
  __shared__ __attribute__((aligned(16))) float PB[4][2][4][64];
  // pre partial B (d 32..51)                                         2 KiB
  __shared__ __attribute__((aligned(16))) float PBb[2][4][64];
  // x-stage: [slot][t-within-interval][32 f16-pairs] (26 data + 6 zero pad)
  __shared__ __attribute__((aligned(16))) unsigned int pxs[2][4][32];  // 1 KiB

  // zero-init hbuf (h[t=-1] = 0) and pxs pads (actually all of pxs)
  ((float*)hbuf)[tid]       = 0.f;
  ((float*)hbuf)[tid + 512] = 0.f;
  if (tid < 256) ((unsigned int*)pxs)[tid] = 0u;

  // role/weights per wave (wv scalar -> role/L/W scalar)
  const float* W;
  float bias = 0.f;
  int role, L;
  if (wv == 7) {
    role = 2; L = 3; W = Wfc; bias = bfc[lane];
  } else if ((wv & 1) == 0) {
    role = 0; L = wv >> 1;
    W = (L == 0) ? Whh0 : (Whh + (L - 1) * 4096);
    if (L > 0) bias = bih[(L - 1) * 64 + lane] + bhh[(L - 1) * 64 + lane];
  } else {
    role = 1; L = (wv + 1) >> 1;
    W = Wih + (L - 1) * 4096;
  }

  h2 w[32];
  {
    const float2* wsrc = (const float2*)(W + lane * 64);
#pragma unroll
    for (int k = 0; k < 32; ++k) {
      float2 v = wsrc[k];
      w[k] = pk2(v.x, v.y);
    }
  }

  // ---- distributed pre0 state (small per wave; keeps live set < 64 VGPR)
  h2 w0[16];                // waves 1,3: half of a Wih0 row
  float bias0 = 0.f;        // wave 1 only
  float4 xr = {0.f, 0.f, 0.f, 0.f};  // wave 5: x regs for interval k+3
  const float4* xg = (const float4*)(x + (long)b * T_STEPS * 52);
  const int xrow = (lane / 13) & 3;   // t-within-interval
  const int xcol = lane % 13;         // float4 index within row
  const bool xact = (lane < 52);      // 52 float4 per interval

  __syncthreads();  // pxs fully zeroed before wave 5 stages data into it

  if (wv == 1) {
    // pre partial A: d = 0..31 (16 pairs), bias folded here
    const float2* w2 = (const float2*)(Wih0 + lane * 52);
#pragma unroll
    for (int q = 0; q < 16; ++q) { float2 v = w2[q]; w0[q] = pk2(v.x, v.y); }
    bias0 = bih0[lane] + bhh0[lane];
  } else if (wv == 3) {
    // pre partial B: d = 32..51 (10 pairs) + 6 zero pairs
    const float2* w2 = (const float2*)(Wih0 + lane * 52);
#pragma unroll
    for (int q = 0; q < 10; ++q) { float2 v = w2[16 + q]; w0[q] = pk2(v.x, v.y); }
#pragma unroll
    for (int q = 10; q < 16; ++q) w0[q] = pk2(0.f, 0.f);
  } else if (wv == 5) {
    // prologue staging: intervals 0,1 -> LDS slots 0,1; interval 2 in regs
    if (xact) {
      float4 xa = xg[0 * 52 + lane];
      float4 xb = xg[1 * 52 + lane];
      xr = xg[2 * 52 + lane];
      pxs[0][xrow][2 * xcol]     = ubc(pk2(xa.x, xa.y));
      pxs[0][xrow][2 * xcol + 1] = ubc(pk2(xa.z, xa.w));
      pxs[1][xrow][2 * xcol]     = ubc(pk2(xb.x, xb.y));
      pxs[1][xrow][2 * xcol + 1] = ubc(pk2(xb.z, xb.w));
    }
  }
  __syncthreads();

  // interval-0 pre partials -> slot 1 (wave 0 reads rd=(0-1)&1=1 at k=0)
  if (wv == 1) {
    float pv;
    PREGEMV16(pv, &pxs[0][0][0], bias0); PB[0][1][0][lane] = pv;
    PREGEMV16(pv, &pxs[0][1][0], bias0); PB[0][1][1][lane] = pv;
    PREGEMV16(pv, &pxs[0][2][0], bias0); PB[0][1][2][lane] = pv;
    PREGEMV16(pv, &pxs[0][3][0], bias0); PB[0][1][3][lane] = pv;
  } else if (wv == 3) {
    float pv;
    PREGEMV16(pv, &pxs[0][0][16], 0.f); PBb[1][0][lane] = pv;
    PREGEMV16(pv, &pxs[0][1][16], 0.f); PBb[1][1][lane] = pv;
    PREGEMV16(pv, &pxs[0][2][16], 0.f); PBb[1][2][lane] = pv;
    PREGEMV16(pv, &pxs[0][3][16], 0.f); PBb[1][3][lane] = pv;
  }
  __syncthreads();

  float* op = out + (long)b * T_STEPS * 64 + lane;

#pragma unroll 1
  for (int k = 0; k < 256 + 7; ++k) {
    const unsigned kk = (unsigned)(k - wv);  // interval index for this wave
    const int rd = (k - 1) & 1;
    const int wr = k & 1;
    if (kk < 256u) {
      if (role == 0) {
        // 4 serial steps: t0 = 4*kk .. t0+3; input parts from PB[L][rd]
        float p0_ = PB[L][rd][0][lane];
        float p1_ = PB[L][rd][1][lane];
        float p2_ = PB[L][rd][2][lane];
        float p3_ = PB[L][rd][3][lane];
        if (L == 0) {  // add partial B (scalar branch)
          p0_ += PBb[rd][0][lane];
          p1_ += PBb[rd][1][lane];
          p2_ += PBb[rd][2][lane];
          p3_ += PBb[rd][3][lane];
        }
        float hv;
        GEMV64(hv, hbuf[L][rd][3], bias);     // h[t0-1] from prev interval
        float h0v = fast_tanh(hv + p0_);
        hbuf[L][wr][0][lane] = (__fp16)h0v;
        GEMV64(hv, hbuf[L][wr][0], bias);     // intra-wave readback
        float h1v = fast_tanh(hv + p1_);
        hbuf[L][wr][1][lane] = (__fp16)h1v;
        GEMV64(hv, hbuf[L][wr][1], bias);
        float h2v = fast_tanh(hv + p2_);
        hbuf[L][wr][2][lane] = (__fp16)h2v;
        GEMV64(hv, hbuf[L][wr][2], bias);
        float h3v = fast_tanh(hv + p3_);
        hbuf[L][wr][3][lane] = (__fp16)h3v;
      } else if (role == 1) {
        // 4 independent GEMVs: P_L[t] = Wih_L h_{L-1}[t]
        float q0, q1, q2, q3;
        GEMV64(q0, hbuf[L - 1][rd][0], 0.f);
        GEMV64(q1, hbuf[L - 1][rd][1], 0.f);
        GEMV64(q2, hbuf[L - 1][rd][2], 0.f);
        GEMV64(q3, hbuf[L - 1][rd][3], 0.f);
        PB[L][wr][0][lane] = q0;
        PB[L][wr][1][lane] = q1;
        PB[L][wr][2][lane] = q2;
        PB[L][wr][3][lane] = q3;
      } else {
        // 4 independent GEMVs: out[t] = Wfc h3[t] + bfc
        float q0, q1, q2, q3;
        GEMV64(q0, hbuf[3][rd][0], bias);
        GEMV64(q1, hbuf[3][rd][1], bias);
        GEMV64(q2, hbuf[3][rd][2], bias);
        GEMV64(q3, hbuf[3][rd][3], bias);
        op[0]   = q0;
        op[64]  = q1;
        op[128] = q2;
        op[192] = q3;
        op += 256;
      }
    }
    // ---- distributed pre0 pipeline (guarded by absolute k) ----
    if (wv == 1) {
      if (k <= 254) {
        // partial A of pre[k+1] from x-stage slot (k+1)&1 into PB[0][k&1]
        const unsigned int* xsrc = &pxs[(k + 1) & 1][0][0];
        float pv;
        PREGEMV16(pv, xsrc + 0 * 32, bias0); PB[0][wr][0][lane] = pv;
        PREGEMV16(pv, xsrc + 1 * 32, bias0); PB[0][wr][1][lane] = pv;
        PREGEMV16(pv, xsrc + 2 * 32, bias0); PB[0][wr][2][lane] = pv;
        PREGEMV16(pv, xsrc + 3 * 32, bias0); PB[0][wr][3][lane] = pv;
      }
    } else if (wv == 3) {
      if (k <= 254) {
        // partial B of pre[k+1] into PBb[k&1]
        const unsigned int* xsrc = &pxs[(k + 1) & 1][0][16];
        float pv;
        PREGEMV16(pv, xsrc + 0 * 32, 0.f); PBb[wr][0][lane] = pv;
        PREGEMV16(pv, xsrc + 1 * 32, 0.f); PBb[wr][1][lane] = pv;
        PREGEMV16(pv, xsrc + 2 * 32, 0.f); PBb[wr][2][lane] = pv;
        PREGEMV16(pv, xsrc + 3 * 32, 0.f); PBb[wr][3][lane] = pv;
      }
    } else if (wv == 5) {
      if (k <= 253 && xact) {
        // stage x for interval k+2 into slot k&1 (read next step as
        // slot (k+2)&1 ✓), then prefetch interval k+3 into regs
        float4 xw = xr;
        if (k <= 252) xr = xg[(k + 3) * 52 + lane];
        pxs[k & 1][xrow][2 * xcol]     = ubc(pk2(xw.x, xw.y));
        pxs[k & 1][xrow][2 * xcol + 1] = ubc(pk2(xw.z, xw.w));
      }
    }
    __syncthreads();  // uniform: every thread, every interval
  }
}

// ---------------------------------------------------------------------------
extern "C" void kernel_launch(void* const* d_in, const int* in_sizes, int n_in,
                              void* d_out, int out_size, void* d_ws,
                              size_t ws_size, hipStream_t stream) {
  const float* x    = (const float*)d_in[0];
  const float* Wih0 = (const float*)d_in[1];
  const float* Whh0 = (const float*)d_in[2];
  const float* bih0 = (const float*)d_in[3];
  const float* bhh0 = (const float*)d_in[4];
  const float* Wih  = (const float*)d_in[5];
  const float* Whh  = (const float*)d_in[6];
  const float* bih  = (const float*)d_in[7];
  const float* bhh  = (const float*)d_in[8];
  const float* Wfc  = (const float*)d_in[9];
  const float* bfc  = (const float*)d_in[10];
  float* out = (float*)d_out;

  const int B = in_sizes[0] / (T_STEPS * 52);  // 512
  (void)d_ws; (void)ws_size;                   // workspace no longer needed

  rnn_fused<<<B, 512, 0, stream>>>(x, Wih0, bih0, bhh0, Whh0, Wih, Whh, bih,
                                   bhh, Wfc, bfc, out);
}